// Round 1
// baseline (40.900 us; speedup 1.0000x reference)
//
#include <hip/hip_runtime.h>
#include <math.h>

#define NTHRESH 50
#define NG 4

// k(p) = #{ t in [0,50) : p > (float)t * 0.02f }  -- exact vs float32 tau grid.
// Estimate via p*50, then fix up against the exact float32 thresholds so any
// rounding at tau boundaries is corrected (loops run at most ~1 iteration).
__device__ __forceinline__ int thresh_count(float p) {
    int k = (int)(p * 50.0f) + 1;
    k = k < 0 ? 0 : (k > NTHRESH ? NTHRESH : k);
    while (k > 0 && !(p > (float)(k - 1) * 0.02f)) --k;
    while (k < NTHRESH && p > (float)k * 0.02f) ++k;
    return k;
}

// ws layout: ws[0..3] = sum of k per group, ws[4..7] = element count per group
__global__ void __launch_bounds__(256)
group_pos_count(const float* __restrict__ pred,
                const int* __restrict__ group,
                unsigned int* __restrict__ ws,
                int n) {
    __shared__ unsigned int s_acc[NG];  // packed (cnt<<16)|ksum per group
    const int tid = threadIdx.x;
    if (tid < NG) s_acc[tid] = 0u;
    __syncthreads();

    // Per-thread packed accumulators: (cnt << 16) | ksum.
    // Safe: with <=1024 blocks * 256 threads, elems/thread <= 20 for N<=5.2M,
    // so per-wave reduced ksum <= 64*20*50 = 64000 < 65536, cnt <= 1280 < 65536.
    unsigned int a0 = 0, a1 = 0, a2 = 0, a3 = 0;

    const int gid = blockIdx.x * blockDim.x + tid;
    const int gstride = gridDim.x * blockDim.x;
    const int n4 = n >> 2;
    const float4* __restrict__ p4 = (const float4*)pred;
    const int4*   __restrict__ g4 = (const int4*)group;

    for (int i = gid; i < n4; i += gstride) {
        float4 p = p4[i];
        int4   g = g4[i];
        unsigned int va = 0x10000u + (unsigned int)thresh_count(p.x);
        unsigned int vb = 0x10000u + (unsigned int)thresh_count(p.y);
        unsigned int vc = 0x10000u + (unsigned int)thresh_count(p.z);
        unsigned int vd = 0x10000u + (unsigned int)thresh_count(p.w);
        int ga = g.x & 3, gb = g.y & 3, gc = g.z & 3, gd = g.w & 3;
        a0 += (ga == 0 ? va : 0u) + (gb == 0 ? vb : 0u) + (gc == 0 ? vc : 0u) + (gd == 0 ? vd : 0u);
        a1 += (ga == 1 ? va : 0u) + (gb == 1 ? vb : 0u) + (gc == 1 ? vc : 0u) + (gd == 1 ? vd : 0u);
        a2 += (ga == 2 ? va : 0u) + (gb == 2 ? vb : 0u) + (gc == 2 ? vc : 0u) + (gd == 2 ? vd : 0u);
        a3 += (ga == 3 ? va : 0u) + (gb == 3 ? vb : 0u) + (gc == 3 ? vc : 0u) + (gd == 3 ? vd : 0u);
    }
    // scalar tail (N=2M is divisible by 4, but stay general)
    for (int i = (n4 << 2) + gid; i < n; i += gstride) {
        float p = pred[i];
        unsigned int v = 0x10000u + (unsigned int)thresh_count(p);
        int g = group[i] & 3;
        if      (g == 0) a0 += v;
        else if (g == 1) a1 += v;
        else if (g == 2) a2 += v;
        else             a3 += v;
    }

    // wave-64 butterfly-style reduce via shfl_down
    #pragma unroll
    for (int off = 32; off >= 1; off >>= 1) {
        a0 += __shfl_down(a0, off);
        a1 += __shfl_down(a1, off);
        a2 += __shfl_down(a2, off);
        a3 += __shfl_down(a3, off);
    }
    if ((tid & 63) == 0) {  // lane 0 of each wave -> LDS (16 LDS atomics/block)
        atomicAdd(&s_acc[0], a0);
        atomicAdd(&s_acc[1], a1);
        atomicAdd(&s_acc[2], a2);
        atomicAdd(&s_acc[3], a3);
    }
    __syncthreads();
    if (tid < NG) {  // 8 global atomics/block
        unsigned int v = s_acc[tid];
        atomicAdd(&ws[tid],      v & 0xFFFFu);  // ksum
        atomicAdd(&ws[NG + tid], v >> 16);      // cnt
    }
}

__global__ void finalize_kernel(const unsigned int* __restrict__ ws,
                                float* __restrict__ out) {
    if (threadIdx.x == 0 && blockIdx.x == 0) {
        double parity[NG];
        #pragma unroll
        for (int g = 0; g < NG; ++g) {
            double ksum = (double)ws[g];
            double cnt  = (double)ws[NG + g];
            parity[g] = ksum / ((double)NTHRESH * (cnt + 1e-10));
        }
        double sum = 0.0, mx = 0.0;
        #pragma unroll
        for (int i = 0; i < NG; ++i)
            #pragma unroll
            for (int j = i + 1; j < NG; ++j) {
                double d = fabs(parity[i] - parity[j]);
                sum += d;
                if (d > mx) mx = d;
            }
        out[0] = (float)(sum / 6.0);  // disparities.mean()
        out[1] = (float)mx;           // disparities.max()
    }
}

extern "C" void kernel_launch(void* const* d_in, const int* in_sizes, int n_in,
                              void* d_out, int out_size, void* d_ws, size_t ws_size,
                              hipStream_t stream) {
    const float* pred  = (const float*)d_in[0];
    // d_in[1] = target (unused by the math, faithful to reference)
    const int*   group = (const int*)d_in[2];
    const int n = in_sizes[0];

    unsigned int* ws = (unsigned int*)d_ws;
    // ws is poisoned 0xAA by the harness and not re-poisoned between replays:
    // zero it every call (async memset is graph-capture safe).
    hipMemsetAsync(d_ws, 0, 2 * NG * sizeof(unsigned int), stream);

    const int threads = 256;
    int n4 = n >> 2;
    int blocks = (n4 + threads - 1) / threads;
    if (blocks > 1024) blocks = 1024;
    if (blocks < 1) blocks = 1;

    group_pos_count<<<blocks, threads, 0, stream>>>(pred, group, ws, n);
    finalize_kernel<<<1, 64, 0, stream>>>(ws, (float*)d_out);
}

// Round 2
// 20.557 us; speedup vs baseline: 1.9896x; 1.9896x over previous
//
#include <hip/hip_runtime.h>
#include <math.h>

#define NTHRESH 50
#define NG 4
#define MAXBLK 1024

// k(p) = #{ t in [0,50) : p > (float)t * 0.02f }  -- exact vs float32 tau grid.
// Estimate via p*50, then fix up against the exact float32 thresholds so any
// rounding at tau boundaries is corrected (loops run at most ~1 iteration).
__device__ __forceinline__ int thresh_count(float p) {
    int k = (int)(p * 50.0f) + 1;
    k = k < 0 ? 0 : (k > NTHRESH ? NTHRESH : k);
    while (k > 0 && !(p > (float)(k - 1) * 0.02f)) --k;
    while (k < NTHRESH && p > (float)k * 0.02f) ++k;
    return k;
}

// partials layout: per block b, 8 uints at partials[b*8]:
//   [ksum_g0, ksum_g1, ksum_g2, ksum_g3, cnt_g0, cnt_g1, cnt_g2, cnt_g3]
// Every slot is written unconditionally every call -> no zero-init of ws
// needed (ws is poisoned 0xAA by the harness; we overwrite before reading).
__global__ void __launch_bounds__(256)
group_pos_count(const float* __restrict__ pred,
                const int* __restrict__ group,
                unsigned int* __restrict__ partials,
                int n) {
    __shared__ unsigned int s_ksum[NG];
    __shared__ unsigned int s_cnt[NG];
    const int tid = threadIdx.x;
    if (tid < NG) { s_ksum[tid] = 0u; s_cnt[tid] = 0u; }
    __syncthreads();

    // Per-thread packed accumulators: (cnt << 16) | ksum.
    // Safe within a wave: grid-stride iterations I = ceil(n/4/262144) = 2 for
    // N=2M, so wave ksum <= 64*2*4*50 = 25600 < 65536. (Unpacked before the
    // block-level combine, which COULD exceed 16 bits.)
    unsigned int a0 = 0, a1 = 0, a2 = 0, a3 = 0;

    const int gid = blockIdx.x * blockDim.x + tid;
    const int gstride = gridDim.x * blockDim.x;
    const int n4 = n >> 2;
    const float4* __restrict__ p4 = (const float4*)pred;
    const int4*   __restrict__ g4 = (const int4*)group;

    for (int i = gid; i < n4; i += gstride) {
        float4 p = p4[i];
        int4   g = g4[i];
        unsigned int va = 0x10000u + (unsigned int)thresh_count(p.x);
        unsigned int vb = 0x10000u + (unsigned int)thresh_count(p.y);
        unsigned int vc = 0x10000u + (unsigned int)thresh_count(p.z);
        unsigned int vd = 0x10000u + (unsigned int)thresh_count(p.w);
        int ga = g.x & 3, gb = g.y & 3, gc = g.z & 3, gd = g.w & 3;
        a0 += (ga == 0 ? va : 0u) + (gb == 0 ? vb : 0u) + (gc == 0 ? vc : 0u) + (gd == 0 ? vd : 0u);
        a1 += (ga == 1 ? va : 0u) + (gb == 1 ? vb : 0u) + (gc == 1 ? vc : 0u) + (gd == 1 ? vd : 0u);
        a2 += (ga == 2 ? va : 0u) + (gb == 2 ? vb : 0u) + (gc == 2 ? vc : 0u) + (gd == 2 ? vd : 0u);
        a3 += (ga == 3 ? va : 0u) + (gb == 3 ? vb : 0u) + (gc == 3 ? vc : 0u) + (gd == 3 ? vd : 0u);
    }
    // scalar tail (N=2M divisible by 4, but stay general)
    for (int i = (n4 << 2) + gid; i < n; i += gstride) {
        float p = pred[i];
        unsigned int v = 0x10000u + (unsigned int)thresh_count(p);
        int g = group[i] & 3;
        if      (g == 0) a0 += v;
        else if (g == 1) a1 += v;
        else if (g == 2) a2 += v;
        else             a3 += v;
    }

    // wave-64 reduce via shfl_down (packed, no overflow per wave)
    #pragma unroll
    for (int off = 32; off >= 1; off >>= 1) {
        a0 += __shfl_down(a0, off);
        a1 += __shfl_down(a1, off);
        a2 += __shfl_down(a2, off);
        a3 += __shfl_down(a3, off);
    }
    if ((tid & 63) == 0) {  // wave leaders: unpack, combine across 4 waves
        atomicAdd(&s_ksum[0], a0 & 0xFFFFu); atomicAdd(&s_cnt[0], a0 >> 16);
        atomicAdd(&s_ksum[1], a1 & 0xFFFFu); atomicAdd(&s_cnt[1], a1 >> 16);
        atomicAdd(&s_ksum[2], a2 & 0xFFFFu); atomicAdd(&s_cnt[2], a2 >> 16);
        atomicAdd(&s_ksum[3], a3 & 0xFFFFu); atomicAdd(&s_cnt[3], a3 >> 16);
    }
    __syncthreads();
    if (tid < NG) {  // unconditional per-block partial write (no atomics, no init)
        partials[blockIdx.x * 8 + tid]      = s_ksum[tid];
        partials[blockIdx.x * 8 + NG + tid] = s_cnt[tid];
    }
}

// Single wave reduces nblocks*8 partial uints (L2-resident) and emits the
// mean/max of the 6 pairwise parity disparities.
__global__ void finalize_kernel(const unsigned int* __restrict__ partials,
                                float* __restrict__ out, int nblocks) {
    const int lane = threadIdx.x;  // 64 threads, 1 wave
    unsigned int ks0 = 0, ks1 = 0, ks2 = 0, ks3 = 0;
    unsigned int ct0 = 0, ct1 = 0, ct2 = 0, ct3 = 0;
    for (int b = lane; b < nblocks; b += 64) {
        const uint4* p = (const uint4*)(partials + b * 8);
        uint4 x = p[0];  // ksum g0..g3
        uint4 y = p[1];  // cnt  g0..g3
        ks0 += x.x; ks1 += x.y; ks2 += x.z; ks3 += x.w;
        ct0 += y.x; ct1 += y.y; ct2 += y.z; ct3 += y.w;
    }
    #pragma unroll
    for (int off = 32; off >= 1; off >>= 1) {
        ks0 += __shfl_down(ks0, off); ks1 += __shfl_down(ks1, off);
        ks2 += __shfl_down(ks2, off); ks3 += __shfl_down(ks3, off);
        ct0 += __shfl_down(ct0, off); ct1 += __shfl_down(ct1, off);
        ct2 += __shfl_down(ct2, off); ct3 += __shfl_down(ct3, off);
    }
    if (lane == 0) {
        double parity[NG];
        parity[0] = (double)ks0 / ((double)NTHRESH * ((double)ct0 + 1e-10));
        parity[1] = (double)ks1 / ((double)NTHRESH * ((double)ct1 + 1e-10));
        parity[2] = (double)ks2 / ((double)NTHRESH * ((double)ct2 + 1e-10));
        parity[3] = (double)ks3 / ((double)NTHRESH * ((double)ct3 + 1e-10));
        double sum = 0.0, mx = 0.0;
        #pragma unroll
        for (int i = 0; i < NG; ++i)
            #pragma unroll
            for (int j = i + 1; j < NG; ++j) {
                double d = fabs(parity[i] - parity[j]);
                sum += d;
                if (d > mx) mx = d;
            }
        out[0] = (float)(sum / 6.0);  // disparities.mean()
        out[1] = (float)mx;           // disparities.max()
    }
}

extern "C" void kernel_launch(void* const* d_in, const int* in_sizes, int n_in,
                              void* d_out, int out_size, void* d_ws, size_t ws_size,
                              hipStream_t stream) {
    const float* pred  = (const float*)d_in[0];
    // d_in[1] = target (unused by the math, faithful to reference)
    const int*   group = (const int*)d_in[2];
    const int n = in_sizes[0];

    unsigned int* partials = (unsigned int*)d_ws;  // needs MAXBLK*8*4 = 32 KB

    const int threads = 256;
    int n4 = n >> 2;
    int blocks = (n4 + threads - 1) / threads;
    if (blocks > MAXBLK) blocks = MAXBLK;
    if (blocks < 1) blocks = 1;

    group_pos_count<<<blocks, threads, 0, stream>>>(pred, group, partials, n);
    finalize_kernel<<<1, 64, 0, stream>>>(partials, (float*)d_out, blocks);
}